// Round 3
// baseline (234.159 us; speedup 1.0000x reference)
//
#include <hip/hip_runtime.h>
#include <math.h>

// TIME_WARPING: not-a-knot cubic spline fit + warped resample, fused.
//
// Math: spline system A M = rhs, A = tridiag(1,4,1) + not-a-knot corner rows:
//   M1 = y0-2y1+y2 (exact); M_{S-2} = y_{S-3}-2y_{S-2}+y_{S-1} (exact)
//   M0 = 2M1 - M2;  M_{S-1} = 2MS2 - M_{S-3}
//   interior: Toeplitz(1,4,1), ghost conditions u_1 = u_{S-2} = 0.
// Toeplitz inverse = conv with G(k) = (-1)^k r^|k| / (2 sqrt3), r = 2-sqrt3,
// truncated at WRAD=7. Fused taps: M = H * y with H = 6 * (G conv [1,-2,1]),
// width +-8 -> reads y directly, no rhs buffer. Edge lanes subtract the
// spurious zero-pad D2 terms (j = -1,0,1 / S-2,S-1,S), the -M1/-MS2 RHS
// moves, and add the boundary-image terms v1*r^(i-1), vS2*r^(S-2-i).
//
// LDS = sy[4096] + sm[4096] = 32768 B exactly -> 5 blocks/CU.
// Pass C: thread owns 4 consecutive outputs, 5 aligned ds_read_b128 / group.
// Pass D: stride-1 lanes -> gather stride ~1 bank (conflict-free), read2.

#define SLEN 4096
#define BLK  256
#define NG   4

__global__ __launch_bounds__(BLK, 4) void time_warp_kernel(
    const float* __restrict__ x,
    const float* __restrict__ scale,
    const int*   __restrict__ apply_mask,
    float* __restrict__ out,
    int C)
{
    __shared__ float sy[SLEN];
    __shared__ float sm[SLEN];

    const int bid = blockIdx.x;   // = b*C + c
    const int b   = bid / C;
    const int t   = threadIdx.x;
    const float* __restrict__ xin = x   + (size_t)bid * SLEN;
    float*       __restrict__ o   = out + (size_t)bid * SLEN;

    // Per-sample apply decision (block-uniform branch before any barrier).
    if (apply_mask[b] == 0) {
        const float4* __restrict__ xi4 = (const float4*)xin;
        float4*       __restrict__ o4  = (float4*)o;
        #pragma unroll
        for (int s = 0; s < NG; ++s)
            o4[t + BLK * s] = xi4[t + BLK * s];
        return;
    }

    // ---- stage y into LDS ----
    {
        const float4* __restrict__ xi4 = (const float4*)xin;
        #pragma unroll
        for (int s = 0; s < NG; ++s)
            *(float4*)&sy[4 * t + 1024 * s] = xi4[t + BLK * s];
    }
    __syncthreads();

    // Green's taps (constant-folded)
    const float log2r = -1.8999686269529532f;   // log2(2 - sqrt(3))
    float Gt[10];
    Gt[0] = 0.28867513459481287f;               // 1/(2 sqrt 3)
    #pragma unroll
    for (int k = 1; k <= 7; ++k) Gt[k] = -Gt[k - 1] * 0.26794919243112270f;
    Gt[8] = 0.0f; Gt[9] = 0.0f;
    float H[9];
    H[0] = 6.0f * (2.0f * Gt[1] - 2.0f * Gt[0]);
    #pragma unroll
    for (int k = 1; k <= 8; ++k) H[k] = 6.0f * (Gt[k - 1] - 2.0f * Gt[k] + Gt[k + 1]);

    auto gax = [&](int d) -> float {   // G(|d|), zero beyond 7 (edge lanes only)
        int a = d < 0 ? -d : d;
        if (a > 7) return 0.0f;
        float g = 0.28867513459481287f * exp2f((float)a * log2r);
        return (a & 1) ? -g : g;
    };

    // ---- pass C: M = H * y (+ edge corrections) ----
    #pragma unroll
    for (int s = 0; s < NG; ++s) {
        const int j0 = 4 * t + 1024 * s;
        float fw[20];                          // y[j0-8 .. j0+11]
        if (j0 >= 8 && j0 <= SLEN - 12) {
            #pragma unroll
            for (int m = 0; m < 5; ++m)
                *(float4*)&fw[4 * m] = *(const float4*)&sy[j0 - 8 + 4 * m];
        } else {                               // 2 lanes/side, clamped scalar
            #pragma unroll
            for (int m = 0; m < 20; ++m) {
                int yi = j0 - 8 + m;
                int yc = yi < 0 ? 0 : (yi > SLEN - 1 ? SLEN - 1 : yi);
                float v = sy[yc];
                fw[m] = (yi < 0 || yi > SLEN - 1) ? 0.0f : v;
            }
        }
        float mv[4];
        #pragma unroll
        for (int e = 0; e < 4; ++e) {
            float acc = H[0] * fw[8 + e];
            #pragma unroll
            for (int k = 1; k <= 8; ++k)
                acc += H[k] * (fw[8 + e - k] + fw[8 + e + k]);
            mv[e] = acc;
        }

        if (j0 <= 12) {                        // threads 0..3 at s==0
            float M1v  = sy[0] - 2.0f * sy[1] + sy[2];
            float fspm = 6.0f * sy[0];                    // spurious j = -1
            float fsp0 = 6.0f * (sy[1] - 2.0f * sy[0]);   // spurious j =  0
            float fsp1 = 6.0f * M1v;                      // spurious j =  1
            float v1 = 0.0f;
            #pragma unroll
            for (int k = 1; k <= 7; ++k)
                v1 += Gt[k] * 6.0f * (sy[k] - 2.0f * sy[k + 1] + sy[k + 2]);
            v1 -= Gt[1] * M1v;
            #pragma unroll
            for (int e = 0; e < 4; ++e) {
                int i = j0 + e;
                float corr = gax(i + 1) * fspm + gax(i) * fsp0
                           + gax(i - 1) * fsp1 + gax(i - 2) * M1v;
                float img = v1 * exp2f((float)(i - 1) * log2r);
                mv[e] = mv[e] - corr + ((i & 1) ? -img : img);
            }
            if (j0 == 0) { mv[1] = M1v; mv[0] = 2.0f * M1v - mv[2]; }
        }
        if (j0 >= SLEN - 16) {                 // threads 252..255 at s==3
            float MS2v = sy[SLEN - 3] - 2.0f * sy[SLEN - 2] + sy[SLEN - 1];
            float fspA = 6.0f * MS2v;                               // j = S-2
            float fspB = 6.0f * (sy[SLEN - 2] - 2.0f * sy[SLEN - 1]); // j = S-1
            float fspC = 6.0f * sy[SLEN - 1];                       // j = S
            float vS2 = 0.0f;
            #pragma unroll
            for (int k = 1; k <= 7; ++k) {
                int j = SLEN - 2 - k;
                vS2 += Gt[k] * 6.0f * (sy[j - 1] - 2.0f * sy[j] + sy[j + 1]);
            }
            vS2 -= Gt[1] * MS2v;
            #pragma unroll
            for (int e = 0; e < 4; ++e) {
                int i = j0 + e;
                float corr = gax(SLEN - 3 - i) * MS2v + gax(SLEN - 2 - i) * fspA
                           + gax(SLEN - 1 - i) * fspB + gax(SLEN - i) * fspC;
                float img = vS2 * exp2f((float)(SLEN - 2 - i) * log2r);
                mv[e] = mv[e] - corr + ((i & 1) ? img : -img);
            }
            if (j0 == SLEN - 4) { mv[2] = MS2v; mv[3] = 2.0f * MS2v - mv[1]; }
        }
        *(float4*)&sm[j0] = make_float4(mv[0], mv[1], mv[2], mv[3]);
    }
    __syncthreads();

    // ---- pass D: warped evaluation, stride-1 lanes (conflict-free gather) ----
    const float sc = scale[b];
    #pragma unroll
    for (int s = 0; s < 16; ++s) {
        const int j = t + BLK * s;
        float w = fminf((float)j * sc, (float)(SLEN - 1));
        int idx = (int)w;
        if (idx > SLEN - 2) idx = SLEN - 2;
        float tt  = w - (float)idx;
        float y0  = sy[idx];
        float y1  = sy[idx + 1];
        float m0  = sm[idx];
        float m1v = sm[idx + 1];
        float bb = (y1 - y0) - (2.0f * m0 + m1v) * (1.0f / 6.0f);
        float cc = 0.5f * m0;
        float dd = (m1v - m0) * (1.0f / 6.0f);
        o[j] = y0 + tt * (bb + tt * (cc + tt * dd));
    }
}

extern "C" void kernel_launch(void* const* d_in, const int* in_sizes, int n_in,
                              void* d_out, int out_size, void* d_ws, size_t ws_size,
                              hipStream_t stream) {
    const float* x     = (const float*)d_in[0];
    const float* scale = (const float*)d_in[1];
    const int*   mask  = (const int*)d_in[2];
    float*       out   = (float*)d_out;

    const int B     = in_sizes[1];            // 128
    const int total = in_sizes[0];            // B*C*S
    const int C     = total / (B * SLEN);     // 64
    const int nblk  = B * C;                  // 8192

    time_warp_kernel<<<nblk, BLK, 0, stream>>>(x, scale, mask, out, C);
}